// Round 2
// baseline (12021.262 us; speedup 1.0000x reference)
//
#include <hip/hip_runtime.h>

// GraphSAGE-CF on MI355X. Round-1 finding: harness feeds the reference's
// declared dtypes — everything float32 (in AND out). The round-0 bf16 guess
// produced an all-zero output via a NaN->relu->0 cascade, bit-identical to
// the empty stub. This version is all-f32.
//
// ws layout (floats):
//   WuT    [2][128][64]  @ 0          (16384)   W transposed: Wt[l][k][j]=W[l][j][k]
//   WiT    [2][128][64]  @ 16384      (16384)
//   neigh_u[200000][64]  @ 32768      (12800000)   f32 scatter accum
//   neigh_i[100000][64]  @ +          (6400000)
//   hu1    [200000][64]  @ +          (12800000)   layer-0 output
//   hi1    [100000][64]  @ +          (6400000)
// total = 153,731,072 bytes

#define N_USERS 200000
#define N_ITEMS 100000
#define N_EDGES 3200000

// ---------- W convert + transpose:  Wt[l][k][j] = W[l][j][k] ----------
__global__ __launch_bounds__(256) void wprep_kernel(
    const float* __restrict__ Wu, const float* __restrict__ Wi,
    float* __restrict__ WuT, float* __restrict__ WiT)
{
    int idx = blockIdx.x * 256 + threadIdx.x;     // 0..32767
    const float* src = Wu;
    float* dst = WuT;
    int i = idx;
    if (idx >= 16384) { src = Wi; dst = WiT; i = idx - 16384; }
    int l = i >> 13;          // layer
    int r = i & 8191;
    int j = r >> 7;           // out col 0..63
    int k = r & 127;          // in  idx 0..127
    dst[l * 8192 + k * 64 + j] = src[i];
}

// ---------- edge scatter: neigh[rows[e]] += vals[e] * h[cols[e]] ----------
// 16 threads per edge, 4 features each. 16 lanes x 16B = one 256B row gather.
__global__ __launch_bounds__(256) void scatter_kernel(
    const int* __restrict__ rows, const int* __restrict__ cols,
    const float* __restrict__ vals, const float* __restrict__ h,
    float* __restrict__ neigh)
{
    int t = blockIdx.x * 256 + threadIdx.x;   // < N_EDGES*16 = 51.2M
    int e = t >> 4;
    int q = t & 15;
    int r = rows[e];
    int c = cols[e];
    float w = vals[e];
    float4 hv = ((const float4*)h)[c * 16 + q];
    float* dst = neigh + (r * 64 + q * 4);
    unsafeAtomicAdd(dst + 0, w * hv.x);
    unsafeAtomicAdd(dst + 1, w * hv.y);
    unsafeAtomicAdd(dst + 2, w * hv.z);
    unsafeAtomicAdd(dst + 3, w * hv.w);
}

// ---------- fused dense transform + relu + l2norm ----------
// out[n,j] = relu( sum_{k<64} hself[n,k]*W[j,k] + sum_{k<64} neigh[n,k]*W[j,64+k] )
// then row-l2-normalized.  Wt[k*64+j] = W[j,k]  (pre-transposed, 128 k-rows).
// Block: 256 thr, 64 rows; thread tile 2 rows x 8 cols.
__global__ __launch_bounds__(256) void transform_kernel(
    const float* __restrict__ hself, const float* __restrict__ neigh,
    const float* __restrict__ Wt, float* __restrict__ out, int N)
{
    __shared__ float Ws[128 * 64];   // 32 KB, stride 64 (conflict-free for 8-col tiles)
    __shared__ float Xs[64 * 66];    // 16.9 KB, pad->stride 66

    const int tid  = threadIdx.x;
    const int row0 = blockIdx.x * 64;

    #pragma unroll
    for (int i = 0; i < 32; ++i) Ws[tid + i * 256] = Wt[tid + i * 256];

    const int tr = tid >> 3;     // 0..31
    const int tc = tid & 7;      // 0..7
    const int r0 = 2 * tr;

    float acc[2][8];
    #pragma unroll
    for (int j = 0; j < 2; ++j)
        #pragma unroll
        for (int c = 0; c < 8; ++c) acc[j][c] = 0.f;

    // ---- phase A: self features (k = 0..63) ----
    #pragma unroll
    for (int i = 0; i < 16; ++i) {
        int idx = tid + i * 256;
        int rr = idx >> 6, cc = idx & 63;
        int gr = row0 + rr; if (gr > N - 1) gr = N - 1;
        Xs[rr * 66 + cc] = hself[gr * 64 + cc];
    }
    __syncthreads();
    #pragma unroll
    for (int k = 0; k < 64; ++k) {
        float a0 = Xs[r0 * 66 + k];
        float a1 = Xs[(r0 + 1) * 66 + k];
        float4 b0 = *(const float4*)&Ws[k * 64 + 8 * tc];
        float4 b1 = *(const float4*)&Ws[k * 64 + 8 * tc + 4];
        float b[8] = {b0.x, b0.y, b0.z, b0.w, b1.x, b1.y, b1.z, b1.w};
        #pragma unroll
        for (int c = 0; c < 8; ++c) {
            acc[0][c] = fmaf(a0, b[c], acc[0][c]);
            acc[1][c] = fmaf(a1, b[c], acc[1][c]);
        }
    }
    __syncthreads();

    // ---- phase B: neighbor features (k = 64..127) ----
    #pragma unroll
    for (int i = 0; i < 16; ++i) {
        int idx = tid + i * 256;
        int rr = idx >> 6, cc = idx & 63;
        int gr = row0 + rr; if (gr > N - 1) gr = N - 1;
        Xs[rr * 66 + cc] = neigh[gr * 64 + cc];
    }
    __syncthreads();
    #pragma unroll
    for (int k = 0; k < 64; ++k) {
        float a0 = Xs[r0 * 66 + k];
        float a1 = Xs[(r0 + 1) * 66 + k];
        float4 b0 = *(const float4*)&Ws[(64 + k) * 64 + 8 * tc];
        float4 b1 = *(const float4*)&Ws[(64 + k) * 64 + 8 * tc + 4];
        float b[8] = {b0.x, b0.y, b0.z, b0.w, b1.x, b1.y, b1.z, b1.w};
        #pragma unroll
        for (int c = 0; c < 8; ++c) {
            acc[0][c] = fmaf(a0, b[c], acc[0][c]);
            acc[1][c] = fmaf(a1, b[c], acc[1][c]);
        }
    }

    // ---- epilogue: relu, row L2 norm (8 lanes per row), store ----
    #pragma unroll
    for (int j = 0; j < 2; ++j) {
        float s = 0.f;
        #pragma unroll
        for (int c = 0; c < 8; ++c) {
            float v = fmaxf(acc[j][c], 0.f);
            acc[j][c] = v;
            s = fmaf(v, v, s);
        }
        s += __shfl_xor(s, 1);
        s += __shfl_xor(s, 2);
        s += __shfl_xor(s, 4);
        float nrm = sqrtf(s);
        float inv = 1.f / fmaxf(nrm, 1e-12f);
        int gr = row0 + r0 + j;
        if (gr < N) {
            float4 o0 = make_float4(acc[j][0]*inv, acc[j][1]*inv, acc[j][2]*inv, acc[j][3]*inv);
            float4 o1 = make_float4(acc[j][4]*inv, acc[j][5]*inv, acc[j][6]*inv, acc[j][7]*inv);
            float* p = out + gr * 64 + 8 * tc;
            *(float4*)p       = o0;
            *(float4*)(p + 4) = o1;
        }
    }
}

extern "C" void kernel_launch(void* const* d_in, const int* in_sizes, int n_in,
                              void* d_out, int out_size, void* d_ws, size_t ws_size,
                              hipStream_t stream)
{
    (void)in_sizes; (void)n_in; (void)out_size; (void)ws_size;

    const float* user_emb = (const float*)d_in[0];
    const float* item_emb = (const float*)d_in[1];
    const float* Wu       = (const float*)d_in[2];
    const float* Wi       = (const float*)d_in[3];
    const int*   u_idx    = (const int*)d_in[4];
    const int*   i_idx    = (const int*)d_in[5];
    const float* w_u2i    = (const float*)d_in[6];
    const float* w_i2u    = (const float*)d_in[7];
    float* out = (float*)d_out;

    float* ws      = (float*)d_ws;
    float* WuT     = ws;                          // 16384
    float* WiT     = WuT + 16384;                 // 16384
    float* neigh_u = WiT + 16384;                 // 12,800,000
    float* neigh_i = neigh_u + (N_USERS * 64);    // 6,400,000
    float* hu1     = neigh_i + (N_ITEMS * 64);    // 12,800,000
    float* hi1     = hu1 + (N_USERS * 64);        // 6,400,000

    wprep_kernel<<<128, 256, 0, stream>>>(Wu, Wi, WuT, WiT);

    const int scatter_blocks = (N_EDGES * 16) / 256;   // 200000
    const int tu_blocks = N_USERS / 64;                // 3125
    const int ti_blocks = (N_ITEMS + 63) / 64;         // 1563

    // ---------------- layer 0 ----------------
    hipMemsetAsync(neigh_u, 0, (size_t)(N_USERS + N_ITEMS) * 64 * 4, stream);
    scatter_kernel<<<scatter_blocks, 256, 0, stream>>>(u_idx, i_idx, w_u2i, item_emb, neigh_u);
    scatter_kernel<<<scatter_blocks, 256, 0, stream>>>(i_idx, u_idx, w_i2u, user_emb, neigh_i);
    transform_kernel<<<tu_blocks, 256, 0, stream>>>(user_emb, neigh_u, WuT, hu1, N_USERS);
    transform_kernel<<<ti_blocks, 256, 0, stream>>>(item_emb, neigh_i, WiT, hi1, N_ITEMS);

    // ---------------- layer 1 ----------------
    hipMemsetAsync(neigh_u, 0, (size_t)(N_USERS + N_ITEMS) * 64 * 4, stream);
    scatter_kernel<<<scatter_blocks, 256, 0, stream>>>(u_idx, i_idx, w_u2i, hi1, neigh_u);
    scatter_kernel<<<scatter_blocks, 256, 0, stream>>>(i_idx, u_idx, w_i2u, hu1, neigh_i);
    transform_kernel<<<tu_blocks, 256, 0, stream>>>(hu1, neigh_u, WuT + 8192, out, N_USERS);
    transform_kernel<<<ti_blocks, 256, 0, stream>>>(hi1, neigh_i, WiT + 8192, out + N_USERS * 64, N_ITEMS);
}

// Round 3
// 7031.224 us; speedup vs baseline: 1.7097x; 1.7097x over previous
//
#include <hip/hip_runtime.h>

// GraphSAGE-CF on MI355X — round 2: kill the f32 atomics.
// Round-1 profile: 4 scatter kernels = 10.8ms of 12.0ms, VALUBusy 0.9%,
// WRITE_SIZE 3.28GB/dispatch = 204.8M atomics x 16B (atomic write path, no
// coalescing). Replace with per-call CSR build (int atomics only) + fused
// gather+GEMM+relu+l2norm. Neighbor buffers eliminated.
//
// ws layout (4-byte words):
//   WuT      [2][128][64]   @ 0          (16384)   Wt[l][k][j] = W[l][j][k]
//   WiT      [2][128][64]   @ 16384      (16384)
//   hu1      [200000][64]   @ 32768      (12800000)  layer-0 user out
//   hi1      [100000][64]   @ 12832768   (6400000)   layer-0 item out
//   rowptr_u [200001]       @ 19232768
//   rowptr_i [100001]       @ 19432769
//   cursor_u [200000]       @ 19532770   (deg during hist; contiguous w/ cursor_i for one memset)
//   cursor_i [100000]       @ 19732770
//   bsum_u[782] bpre_u[782] bsum_i[391] bpre_i[391] @ 19832770
//   edges_u  uint2[3200000] @ 19835116   (item_col, w_u2i bits), grouped by user row
//   edges_i  uint2[3200000] @ 26235116   (user_col, w_i2u bits), grouped by item row
// total = 130,540,464 bytes

#define N_USERS 200000
#define N_ITEMS 100000
#define N_EDGES 3200000
#define NB_U 782      // ceil(200000/256)
#define NB_I 391      // ceil(100000/256)

// ---------- W convert + transpose:  Wt[l][k][j] = W[l][j][k] ----------
__global__ __launch_bounds__(256) void wprep_kernel(
    const float* __restrict__ Wu, const float* __restrict__ Wi,
    float* __restrict__ WuT, float* __restrict__ WiT)
{
    int idx = blockIdx.x * 256 + threadIdx.x;     // 0..32767
    const float* src = Wu;
    float* dst = WuT;
    int i = idx;
    if (idx >= 16384) { src = Wi; dst = WiT; i = idx - 16384; }
    int l = i >> 13;
    int r = i & 8191;
    int j = r >> 7;           // out col 0..63
    int k = r & 127;          // in  idx 0..127
    dst[l * 8192 + k * 64 + j] = src[i];
}

// ---------- degree histogram (both sides in one launch) ----------
__global__ __launch_bounds__(256) void hist_kernel(
    const int* __restrict__ u_idx, const int* __restrict__ i_idx,
    int* __restrict__ deg_u, int* __restrict__ deg_i)
{
    int t = blockIdx.x * 256 + threadIdx.x;     // < 2E
    if (t < N_EDGES) atomicAdd(&deg_u[u_idx[t]], 1);
    else             atomicAdd(&deg_i[i_idx[t - N_EDGES]], 1);
}

// ---------- scan phase A: per-block sums ----------
__global__ __launch_bounds__(256) void scanA_kernel(
    const int* __restrict__ deg_u, const int* __restrict__ deg_i,
    int* __restrict__ bsum_u, int* __restrict__ bsum_i)
{
    int b = blockIdx.x;
    const int* deg; int n; int* bs; int bb;
    if (b < NB_U) { deg = deg_u; n = N_USERS; bs = bsum_u; bb = b; }
    else          { deg = deg_i; n = N_ITEMS; bs = bsum_i; bb = b - NB_U; }
    int i = bb * 256 + threadIdx.x;
    int v = (i < n) ? deg[i] : 0;
    #pragma unroll
    for (int off = 1; off < 64; off <<= 1) v += __shfl_xor(v, off);
    __shared__ int ws4[4];
    int wv = threadIdx.x >> 6;
    if ((threadIdx.x & 63) == 0) ws4[wv] = v;
    __syncthreads();
    if (threadIdx.x == 0) bs[bb] = ws4[0] + ws4[1] + ws4[2] + ws4[3];
}

// ---------- scan phase B: exclusive scan of block sums (one block each) ----------
__global__ __launch_bounds__(1024) void scanB_kernel(
    const int* __restrict__ bsum_u, int* __restrict__ bpre_u,
    const int* __restrict__ bsum_i, int* __restrict__ bpre_i)
{
    __shared__ int s[1024];
    const int* src; int* dst; int n;
    if (blockIdx.x == 0) { src = bsum_u; dst = bpre_u; n = NB_U; }
    else                 { src = bsum_i; dst = bpre_i; n = NB_I; }
    int t = threadIdx.x;
    int v = (t < n) ? src[t] : 0;
    s[t] = v; __syncthreads();
    #pragma unroll
    for (int off = 1; off < 1024; off <<= 1) {
        int x = (t >= off) ? s[t - off] : 0;
        __syncthreads();
        s[t] += x;
        __syncthreads();
    }
    if (t < n) dst[t] = s[t] - v;   // exclusive
}

// ---------- scan phase C: rowptr = bpre + intra-block exclusive; cursor=rowptr ----------
__global__ __launch_bounds__(256) void scanC_kernel(
    int* __restrict__ cur_u, int* __restrict__ cur_i,
    const int* __restrict__ bpre_u, const int* __restrict__ bpre_i,
    int* __restrict__ rowptr_u, int* __restrict__ rowptr_i)
{
    int b = blockIdx.x;
    int* cur; int n; const int* bpre; int* rowptr; int bb;
    if (b < NB_U) { cur = cur_u; n = N_USERS; bpre = bpre_u; rowptr = rowptr_u; bb = b; }
    else          { cur = cur_i; n = N_ITEMS; bpre = bpre_i; rowptr = rowptr_i; bb = b - NB_U; }
    int t = threadIdx.x;
    int i = bb * 256 + t;
    int deg = (i < n) ? cur[i] : 0;
    __shared__ int s[256];
    s[t] = deg; __syncthreads();
    #pragma unroll
    for (int off = 1; off < 256; off <<= 1) {
        int x = (t >= off) ? s[t - off] : 0;
        __syncthreads();
        s[t] += x;
        __syncthreads();
    }
    int val = bpre[bb] + (s[t] - deg);
    if (i < n) { rowptr[i] = val; cur[i] = val; }
    if (b == 0 && t == 0) { rowptr_u[N_USERS] = N_EDGES; rowptr_i[N_ITEMS] = N_EDGES; }
}

// ---------- CSR fill: edges[p] = (col, w_bits), p = cursor[row]++ ----------
__global__ __launch_bounds__(256) void fill_kernel(
    const int* __restrict__ u_idx, const int* __restrict__ i_idx,
    const float* __restrict__ w_u2i, const float* __restrict__ w_i2u,
    int* __restrict__ cur_u, int* __restrict__ cur_i,
    uint2* __restrict__ edges_u, uint2* __restrict__ edges_i)
{
    int t = blockIdx.x * 256 + threadIdx.x;     // < 2E
    if (t < N_EDGES) {
        int r = u_idx[t];
        int p = atomicAdd(&cur_u[r], 1);
        edges_u[p] = make_uint2((unsigned)i_idx[t], __float_as_uint(w_u2i[t]));
    } else {
        int e = t - N_EDGES;
        int r = i_idx[e];
        int p = atomicAdd(&cur_i[r], 1);
        edges_i[p] = make_uint2((unsigned)u_idx[e], __float_as_uint(w_i2u[e]));
    }
}

// ---------- fused gather + dense transform + relu + l2norm ----------
// out[n,j] = relu( sum_k hself[n,k]*W[j,k] + sum_k neigh[n,k]*W[j,64+k] ),
// row-l2-normalized; neigh[n,:] = sum_{e in row n} w_e * hsrc[col_e,:] gathered
// on the fly (lane = feature -> 256B coalesced read per edge, L3-resident).
__global__ __launch_bounds__(256) void transform_fused_kernel(
    const float* __restrict__ hself, const float* __restrict__ hsrc,
    const int* __restrict__ rowptr, const uint2* __restrict__ edges,
    const float* __restrict__ Wt, float* __restrict__ out, int N)
{
    __shared__ float Ws[128 * 64];   // 32 KB
    __shared__ float Xs[64 * 66];    // 16.9 KB, pad->stride 66

    const int tid  = threadIdx.x;
    const int row0 = blockIdx.x * 64;

    #pragma unroll
    for (int i = 0; i < 32; ++i) Ws[tid + i * 256] = Wt[tid + i * 256];

    const int tr = tid >> 3;     // 0..31
    const int tc = tid & 7;      // 0..7
    const int r0 = 2 * tr;

    float acc[2][8];
    #pragma unroll
    for (int j = 0; j < 2; ++j)
        #pragma unroll
        for (int c = 0; c < 8; ++c) acc[j][c] = 0.f;

    // ---- phase A: self features (k = 0..63) ----
    #pragma unroll
    for (int i = 0; i < 16; ++i) {
        int idx = tid + i * 256;
        int rr = idx >> 6, cc = idx & 63;
        int gr = row0 + rr; if (gr > N - 1) gr = N - 1;
        Xs[rr * 66 + cc] = hself[gr * 64 + cc];
    }
    __syncthreads();
    #pragma unroll
    for (int k = 0; k < 64; ++k) {
        float a0 = Xs[r0 * 66 + k];
        float a1 = Xs[(r0 + 1) * 66 + k];
        float4 b0 = *(const float4*)&Ws[k * 64 + 8 * tc];
        float4 b1 = *(const float4*)&Ws[k * 64 + 8 * tc + 4];
        float b[8] = {b0.x, b0.y, b0.z, b0.w, b1.x, b1.y, b1.z, b1.w};
        #pragma unroll
        for (int c = 0; c < 8; ++c) {
            acc[0][c] = fmaf(a0, b[c], acc[0][c]);
            acc[1][c] = fmaf(a1, b[c], acc[1][c]);
        }
    }
    __syncthreads();

    // ---- gather neighbor rows into Xs (wave per 16 rows, lane = feature) ----
    {
        const int wv = tid >> 6;      // 0..3
        const int ln = tid & 63;      // feature
        #pragma unroll 1
        for (int rl = 0; rl < 16; ++rl) {
            int lr = wv * 16 + rl;
            int r  = row0 + lr;
            float a = 0.f;
            if (r < N) {
                int e0 = rowptr[r], e1 = rowptr[r + 1];
                int mid = (e0 + e1 + 1) >> 1;   // [e0,mid) >= [mid,e1)
                float a2 = 0.f;
                int na = mid - e0;
                for (int k = 0; k < na; ++k) {
                    uint2 ea = edges[e0 + k];
                    a = fmaf(__uint_as_float(ea.y), hsrc[(size_t)ea.x * 64 + ln], a);
                    int eb = mid + k;
                    if (eb < e1) {
                        uint2 eB = edges[eb];
                        a2 = fmaf(__uint_as_float(eB.y), hsrc[(size_t)eB.x * 64 + ln], a2);
                    }
                }
                a += a2;
            }
            Xs[lr * 66 + ln] = a;
        }
    }
    __syncthreads();

    // ---- phase B: neighbor features (k = 64..127) ----
    #pragma unroll
    for (int k = 0; k < 64; ++k) {
        float a0 = Xs[r0 * 66 + k];
        float a1 = Xs[(r0 + 1) * 66 + k];
        float4 b0 = *(const float4*)&Ws[(64 + k) * 64 + 8 * tc];
        float4 b1 = *(const float4*)&Ws[(64 + k) * 64 + 8 * tc + 4];
        float b[8] = {b0.x, b0.y, b0.z, b0.w, b1.x, b1.y, b1.z, b1.w};
        #pragma unroll
        for (int c = 0; c < 8; ++c) {
            acc[0][c] = fmaf(a0, b[c], acc[0][c]);
            acc[1][c] = fmaf(a1, b[c], acc[1][c]);
        }
    }

    // ---- epilogue: relu, row L2 norm (8 lanes per row), store ----
    #pragma unroll
    for (int j = 0; j < 2; ++j) {
        float s = 0.f;
        #pragma unroll
        for (int c = 0; c < 8; ++c) {
            float v = fmaxf(acc[j][c], 0.f);
            acc[j][c] = v;
            s = fmaf(v, v, s);
        }
        s += __shfl_xor(s, 1);
        s += __shfl_xor(s, 2);
        s += __shfl_xor(s, 4);
        float nrm = sqrtf(s);
        float inv = 1.f / fmaxf(nrm, 1e-12f);
        int gr = row0 + r0 + j;
        if (gr < N) {
            float4 o0 = make_float4(acc[j][0]*inv, acc[j][1]*inv, acc[j][2]*inv, acc[j][3]*inv);
            float4 o1 = make_float4(acc[j][4]*inv, acc[j][5]*inv, acc[j][6]*inv, acc[j][7]*inv);
            float* p = out + gr * 64 + 8 * tc;
            *(float4*)p       = o0;
            *(float4*)(p + 4) = o1;
        }
    }
}

extern "C" void kernel_launch(void* const* d_in, const int* in_sizes, int n_in,
                              void* d_out, int out_size, void* d_ws, size_t ws_size,
                              hipStream_t stream)
{
    (void)in_sizes; (void)n_in; (void)out_size; (void)ws_size;

    const float* user_emb = (const float*)d_in[0];
    const float* item_emb = (const float*)d_in[1];
    const float* Wu       = (const float*)d_in[2];
    const float* Wi       = (const float*)d_in[3];
    const int*   u_idx    = (const int*)d_in[4];
    const int*   i_idx    = (const int*)d_in[5];
    const float* w_u2i    = (const float*)d_in[6];
    const float* w_i2u    = (const float*)d_in[7];
    float* out = (float*)d_out;

    float* ws       = (float*)d_ws;
    float* WuT      = ws;                       // 16384
    float* WiT      = WuT + 16384;              // 16384
    float* hu1      = WiT + 16384;              // 12,800,000
    float* hi1      = hu1 + N_USERS * 64;       // 6,400,000
    int*   rowptr_u = (int*)(hi1 + N_ITEMS * 64);     // 200001
    int*   rowptr_i = rowptr_u + (N_USERS + 1);       // 100001
    int*   cursor_u = rowptr_i + (N_ITEMS + 1);       // 200000 (deg during hist)
    int*   cursor_i = cursor_u + N_USERS;             // 100000
    int*   bsum_u   = cursor_i + N_ITEMS;             // 782
    int*   bpre_u   = bsum_u + NB_U;                  // 782
    int*   bsum_i   = bpre_u + NB_U;                  // 391
    int*   bpre_i   = bsum_i + NB_I;                  // 391
    uint2* edges_u  = (uint2*)(bpre_i + NB_I);        // 3,200,000 uint2
    uint2* edges_i  = edges_u + N_EDGES;              // 3,200,000 uint2

    const int tu_blocks = (N_USERS + 63) / 64;        // 3125
    const int ti_blocks = (N_ITEMS + 63) / 64;        // 1563
    const int e2_blocks = (2 * N_EDGES) / 256;        // 25000

    // ---- CSR build (both sides) ----
    wprep_kernel<<<128, 256, 0, stream>>>(Wu, Wi, WuT, WiT);
    hipMemsetAsync(cursor_u, 0, (size_t)(N_USERS + N_ITEMS) * 4, stream);
    hist_kernel<<<e2_blocks, 256, 0, stream>>>(u_idx, i_idx, cursor_u, cursor_i);
    scanA_kernel<<<NB_U + NB_I, 256, 0, stream>>>(cursor_u, cursor_i, bsum_u, bsum_i);
    scanB_kernel<<<2, 1024, 0, stream>>>(bsum_u, bpre_u, bsum_i, bpre_i);
    scanC_kernel<<<NB_U + NB_I, 256, 0, stream>>>(cursor_u, cursor_i, bpre_u, bpre_i, rowptr_u, rowptr_i);
    fill_kernel<<<e2_blocks, 256, 0, stream>>>(u_idx, i_idx, w_u2i, w_i2u,
                                               cursor_u, cursor_i, edges_u, edges_i);

    // ---- layer 0 ----
    transform_fused_kernel<<<tu_blocks, 256, 0, stream>>>(user_emb, item_emb, rowptr_u, edges_u, WuT, hu1, N_USERS);
    transform_fused_kernel<<<ti_blocks, 256, 0, stream>>>(item_emb, user_emb, rowptr_i, edges_i, WiT, hi1, N_ITEMS);

    // ---- layer 1 ----
    transform_fused_kernel<<<tu_blocks, 256, 0, stream>>>(hu1, hi1, rowptr_u, edges_u, WuT + 8192, out, N_USERS);
    transform_fused_kernel<<<ti_blocks, 256, 0, stream>>>(hi1, hu1, rowptr_i, edges_i, WiT + 8192, out + (size_t)N_USERS * 64, N_ITEMS);
}

// Round 4
// 1745.459 us; speedup vs baseline: 6.8872x; 4.0283x over previous
//
#include <hip/hip_runtime.h>

// GraphSAGE-CF on MI355X — round 3: fix the latency-bound gather.
// Round-2 profile: transform_fused 4x1617us, VGPR=256, LDS=49.6KB,
// Occupancy 11%, VALUBusy 6% -> serial dependent-load gather at 2 loads in
// flight per wave. This round: 16 interleaved branchless gather chains per
// wave, VGPR capped at 128 (__launch_bounds__(256,4), unroll-8 GEMM), LDS
// 33.8KB (Ws reloaded in halves) -> 4 blocks/CU.
//
// ws layout (4-byte words):
//   WuT      [2][128][64]   Wt[l][k][j] = W[l][j][k]
//   WiT      [2][128][64]
//   hu1      [200000][64]   layer-0 user out
//   hi1      [100000][64]   layer-0 item out
//   rowptr_u [200001]  rowptr_i [100001]
//   cursor_u [200000]  cursor_i [100000]   (deg during hist)
//   bsum_u[782] bpre_u[782] bsum_i[391] bpre_i[391]
//   edges_u  uint2[3200000]  (item_col, w_u2i bits), grouped by user row
//   edges_i  uint2[3200000]  (user_col, w_i2u bits), grouped by item row

#define N_USERS 200000
#define N_ITEMS 100000
#define N_EDGES 3200000
#define NB_U 782      // ceil(200000/256)
#define NB_I 391      // ceil(100000/256)

// ---------- W convert + transpose:  Wt[l][k][j] = W[l][j][k] ----------
__global__ __launch_bounds__(256) void wprep_kernel(
    const float* __restrict__ Wu, const float* __restrict__ Wi,
    float* __restrict__ WuT, float* __restrict__ WiT)
{
    int idx = blockIdx.x * 256 + threadIdx.x;     // 0..32767
    const float* src = Wu;
    float* dst = WuT;
    int i = idx;
    if (idx >= 16384) { src = Wi; dst = WiT; i = idx - 16384; }
    int l = i >> 13;
    int r = i & 8191;
    int j = r >> 7;           // out col 0..63
    int k = r & 127;          // in  idx 0..127
    dst[l * 8192 + k * 64 + j] = src[i];
}

// ---------- degree histogram (both sides in one launch) ----------
__global__ __launch_bounds__(256) void hist_kernel(
    const int* __restrict__ u_idx, const int* __restrict__ i_idx,
    int* __restrict__ deg_u, int* __restrict__ deg_i)
{
    int t = blockIdx.x * 256 + threadIdx.x;     // < 2E
    if (t < N_EDGES) atomicAdd(&deg_u[u_idx[t]], 1);
    else             atomicAdd(&deg_i[i_idx[t - N_EDGES]], 1);
}

// ---------- scan phase A: per-block sums ----------
__global__ __launch_bounds__(256) void scanA_kernel(
    const int* __restrict__ deg_u, const int* __restrict__ deg_i,
    int* __restrict__ bsum_u, int* __restrict__ bsum_i)
{
    int b = blockIdx.x;
    const int* deg; int n; int* bs; int bb;
    if (b < NB_U) { deg = deg_u; n = N_USERS; bs = bsum_u; bb = b; }
    else          { deg = deg_i; n = N_ITEMS; bs = bsum_i; bb = b - NB_U; }
    int i = bb * 256 + threadIdx.x;
    int v = (i < n) ? deg[i] : 0;
    #pragma unroll
    for (int off = 1; off < 64; off <<= 1) v += __shfl_xor(v, off);
    __shared__ int ws4[4];
    int wv = threadIdx.x >> 6;
    if ((threadIdx.x & 63) == 0) ws4[wv] = v;
    __syncthreads();
    if (threadIdx.x == 0) bs[bb] = ws4[0] + ws4[1] + ws4[2] + ws4[3];
}

// ---------- scan phase B: exclusive scan of block sums ----------
__global__ __launch_bounds__(1024) void scanB_kernel(
    const int* __restrict__ bsum_u, int* __restrict__ bpre_u,
    const int* __restrict__ bsum_i, int* __restrict__ bpre_i)
{
    __shared__ int s[1024];
    const int* src; int* dst; int n;
    if (blockIdx.x == 0) { src = bsum_u; dst = bpre_u; n = NB_U; }
    else                 { src = bsum_i; dst = bpre_i; n = NB_I; }
    int t = threadIdx.x;
    int v = (t < n) ? src[t] : 0;
    s[t] = v; __syncthreads();
    #pragma unroll
    for (int off = 1; off < 1024; off <<= 1) {
        int x = (t >= off) ? s[t - off] : 0;
        __syncthreads();
        s[t] += x;
        __syncthreads();
    }
    if (t < n) dst[t] = s[t] - v;   // exclusive
}

// ---------- scan phase C: rowptr = bpre + intra-block exclusive ----------
__global__ __launch_bounds__(256) void scanC_kernel(
    int* __restrict__ cur_u, int* __restrict__ cur_i,
    const int* __restrict__ bpre_u, const int* __restrict__ bpre_i,
    int* __restrict__ rowptr_u, int* __restrict__ rowptr_i)
{
    int b = blockIdx.x;
    int* cur; int n; const int* bpre; int* rowptr; int bb;
    if (b < NB_U) { cur = cur_u; n = N_USERS; bpre = bpre_u; rowptr = rowptr_u; bb = b; }
    else          { cur = cur_i; n = N_ITEMS; bpre = bpre_i; rowptr = rowptr_i; bb = b - NB_U; }
    int t = threadIdx.x;
    int i = bb * 256 + t;
    int deg = (i < n) ? cur[i] : 0;
    __shared__ int s[256];
    s[t] = deg; __syncthreads();
    #pragma unroll
    for (int off = 1; off < 256; off <<= 1) {
        int x = (t >= off) ? s[t - off] : 0;
        __syncthreads();
        s[t] += x;
        __syncthreads();
    }
    int val = bpre[bb] + (s[t] - deg);
    if (i < n) { rowptr[i] = val; cur[i] = val; }
    if (b == 0 && t == 0) { rowptr_u[N_USERS] = N_EDGES; rowptr_i[N_ITEMS] = N_EDGES; }
}

// ---------- CSR fill ----------
__global__ __launch_bounds__(256) void fill_kernel(
    const int* __restrict__ u_idx, const int* __restrict__ i_idx,
    const float* __restrict__ w_u2i, const float* __restrict__ w_i2u,
    int* __restrict__ cur_u, int* __restrict__ cur_i,
    uint2* __restrict__ edges_u, uint2* __restrict__ edges_i)
{
    int t = blockIdx.x * 256 + threadIdx.x;     // < 2E
    if (t < N_EDGES) {
        int r = u_idx[t];
        int p = atomicAdd(&cur_u[r], 1);
        edges_u[p] = make_uint2((unsigned)i_idx[t], __float_as_uint(w_u2i[t]));
    } else {
        int e = t - N_EDGES;
        int r = i_idx[e];
        int p = atomicAdd(&cur_i[r], 1);
        edges_i[p] = make_uint2((unsigned)u_idx[e], __float_as_uint(w_i2u[e]));
    }
}

// ---------- fused gather + dense transform + relu + l2norm ----------
// Gather: each wave owns 16 consecutive rows (lane = feature); 16 interleaved
// branchless chains -> 32 independent loads in flight per wave.
__global__ __launch_bounds__(256, 4) void transform_fused_kernel(
    const float* __restrict__ hself, const float* __restrict__ hsrc,
    const int* __restrict__ rowptr, const uint2* __restrict__ edges,
    const float* __restrict__ Wt, float* __restrict__ out, int N)
{
    __shared__ float Ws[64 * 64];    // 16 KB — one half of Wt at a time
    __shared__ float Xs[64 * 68];    // 17 KB, stride 68 (16B-aligned rows)

    const int tid  = threadIdx.x;
    const int row0 = blockIdx.x * 64;

    // ---- stage Ws half A (k=0..63) and self-feature tile ----
    #pragma unroll
    for (int i = 0; i < 16; ++i) Ws[tid + i * 256] = Wt[tid + i * 256];
    #pragma unroll
    for (int i = 0; i < 16; ++i) {
        int idx = tid + i * 256;
        int rr = idx >> 6, cc = idx & 63;
        int gr = row0 + rr; if (gr > N - 1) gr = N - 1;
        Xs[rr * 68 + cc] = hself[gr * 64 + cc];
    }
    __syncthreads();

    const int tr = tid >> 3;     // 0..31
    const int tc = tid & 7;      // 0..7
    const int r0 = 2 * tr;

    float acc[2][8];
    #pragma unroll
    for (int j = 0; j < 2; ++j)
        #pragma unroll
        for (int c = 0; c < 8; ++c) acc[j][c] = 0.f;

    // ---- GEMM phase A: self features ----
    #pragma unroll 8
    for (int k = 0; k < 64; ++k) {
        float a0 = Xs[r0 * 68 + k];
        float a1 = Xs[(r0 + 1) * 68 + k];
        float4 b0 = *(const float4*)&Ws[k * 64 + 8 * tc];
        float4 b1 = *(const float4*)&Ws[k * 64 + 8 * tc + 4];
        float b[8] = {b0.x, b0.y, b0.z, b0.w, b1.x, b1.y, b1.z, b1.w};
        #pragma unroll
        for (int c = 0; c < 8; ++c) {
            acc[0][c] = fmaf(a0, b[c], acc[0][c]);
            acc[1][c] = fmaf(a1, b[c], acc[1][c]);
        }
    }
    __syncthreads();   // all waves done with Ws-A and self Xs

    // ---- reload Ws half B (k=64..127) ----
    {
        const float4* src = (const float4*)(Wt + 4096);
        float4* dst = (float4*)Ws;
        #pragma unroll
        for (int i = 0; i < 4; ++i) dst[tid + i * 256] = src[tid + i * 256];
    }

    // ---- gather: wave wv owns rows [wv*16, wv*16+16), lane = feature ----
    {
        const int wv = tid >> 6;
        const int ln = tid & 63;
        const int rbase = row0 + wv * 16;

        float gacc[16];
        int ecur[16], eend[16];
        #pragma unroll
        for (int rl = 0; rl < 16; ++rl) {
            int r = rbase + rl;
            if (r < N) { ecur[rl] = rowptr[r]; eend[rl] = rowptr[r + 1]; }
            else       { ecur[rl] = 0;         eend[rl] = 0; }
            gacc[rl] = 0.f;
        }
        int dmax = 0;
        #pragma unroll
        for (int rl = 0; rl < 16; ++rl) dmax = max(dmax, eend[rl] - ecur[rl]);

        for (int it = 0; it < dmax; ++it) {
            int   col[16];
            float wgt[16];
            #pragma unroll
            for (int rl = 0; rl < 16; ++rl) {
                bool v = ecur[rl] < eend[rl];
                int idx = v ? ecur[rl] : 0;     // branchless: clamp to edge 0
                uint2 e = edges[idx];
                col[rl] = (int)e.x * 64 + ln;
                wgt[rl] = v ? __uint_as_float(e.y) : 0.f;
                ecur[rl] += v ? 1 : 0;
            }
            #pragma unroll
            for (int rl = 0; rl < 16; ++rl)
                gacc[rl] = fmaf(wgt[rl], hsrc[col[rl]], gacc[rl]);
        }
        #pragma unroll
        for (int rl = 0; rl < 16; ++rl)
            Xs[(wv * 16 + rl) * 68 + ln] = gacc[rl];
    }
    __syncthreads();

    // ---- GEMM phase B: neighbor features ----
    #pragma unroll 8
    for (int k = 0; k < 64; ++k) {
        float a0 = Xs[r0 * 68 + k];
        float a1 = Xs[(r0 + 1) * 68 + k];
        float4 b0 = *(const float4*)&Ws[k * 64 + 8 * tc];
        float4 b1 = *(const float4*)&Ws[k * 64 + 8 * tc + 4];
        float b[8] = {b0.x, b0.y, b0.z, b0.w, b1.x, b1.y, b1.z, b1.w};
        #pragma unroll
        for (int c = 0; c < 8; ++c) {
            acc[0][c] = fmaf(a0, b[c], acc[0][c]);
            acc[1][c] = fmaf(a1, b[c], acc[1][c]);
        }
    }

    // ---- epilogue: relu, row L2 norm (8 lanes per row), store ----
    #pragma unroll
    for (int j = 0; j < 2; ++j) {
        float s = 0.f;
        #pragma unroll
        for (int c = 0; c < 8; ++c) {
            float v = fmaxf(acc[j][c], 0.f);
            acc[j][c] = v;
            s = fmaf(v, v, s);
        }
        s += __shfl_xor(s, 1);
        s += __shfl_xor(s, 2);
        s += __shfl_xor(s, 4);
        float nrm = sqrtf(s);
        float inv = 1.f / fmaxf(nrm, 1e-12f);
        int gr = row0 + r0 + j;
        if (gr < N) {
            float4 o0 = make_float4(acc[j][0]*inv, acc[j][1]*inv, acc[j][2]*inv, acc[j][3]*inv);
            float4 o1 = make_float4(acc[j][4]*inv, acc[j][5]*inv, acc[j][6]*inv, acc[j][7]*inv);
            float* p = out + gr * 64 + 8 * tc;
            *(float4*)p       = o0;
            *(float4*)(p + 4) = o1;
        }
    }
}

extern "C" void kernel_launch(void* const* d_in, const int* in_sizes, int n_in,
                              void* d_out, int out_size, void* d_ws, size_t ws_size,
                              hipStream_t stream)
{
    (void)in_sizes; (void)n_in; (void)out_size; (void)ws_size;

    const float* user_emb = (const float*)d_in[0];
    const float* item_emb = (const float*)d_in[1];
    const float* Wu       = (const float*)d_in[2];
    const float* Wi       = (const float*)d_in[3];
    const int*   u_idx    = (const int*)d_in[4];
    const int*   i_idx    = (const int*)d_in[5];
    const float* w_u2i    = (const float*)d_in[6];
    const float* w_i2u    = (const float*)d_in[7];
    float* out = (float*)d_out;

    float* ws       = (float*)d_ws;
    float* WuT      = ws;                       // 16384
    float* WiT      = WuT + 16384;              // 16384
    float* hu1      = WiT + 16384;              // 12,800,000
    float* hi1      = hu1 + N_USERS * 64;       // 6,400,000
    int*   rowptr_u = (int*)(hi1 + N_ITEMS * 64);     // 200001
    int*   rowptr_i = rowptr_u + (N_USERS + 1);       // 100001
    int*   cursor_u = rowptr_i + (N_ITEMS + 1);       // 200000
    int*   cursor_i = cursor_u + N_USERS;             // 100000
    int*   bsum_u   = cursor_i + N_ITEMS;
    int*   bpre_u   = bsum_u + NB_U;
    int*   bsum_i   = bpre_u + NB_U;
    int*   bpre_i   = bsum_i + NB_I;
    uint2* edges_u  = (uint2*)(bpre_i + NB_I);
    uint2* edges_i  = edges_u + N_EDGES;

    const int tu_blocks = (N_USERS + 63) / 64;        // 3125
    const int ti_blocks = (N_ITEMS + 63) / 64;        // 1563
    const int e2_blocks = (2 * N_EDGES) / 256;        // 25000

    // ---- CSR build (both sides) ----
    wprep_kernel<<<128, 256, 0, stream>>>(Wu, Wi, WuT, WiT);
    hipMemsetAsync(cursor_u, 0, (size_t)(N_USERS + N_ITEMS) * 4, stream);
    hist_kernel<<<e2_blocks, 256, 0, stream>>>(u_idx, i_idx, cursor_u, cursor_i);
    scanA_kernel<<<NB_U + NB_I, 256, 0, stream>>>(cursor_u, cursor_i, bsum_u, bsum_i);
    scanB_kernel<<<2, 1024, 0, stream>>>(bsum_u, bpre_u, bsum_i, bpre_i);
    scanC_kernel<<<NB_U + NB_I, 256, 0, stream>>>(cursor_u, cursor_i, bpre_u, bpre_i, rowptr_u, rowptr_i);
    fill_kernel<<<e2_blocks, 256, 0, stream>>>(u_idx, i_idx, w_u2i, w_i2u,
                                               cursor_u, cursor_i, edges_u, edges_i);

    // ---- layer 0 ----
    transform_fused_kernel<<<tu_blocks, 256, 0, stream>>>(user_emb, item_emb, rowptr_u, edges_u, WuT, hu1, N_USERS);
    transform_fused_kernel<<<ti_blocks, 256, 0, stream>>>(item_emb, user_emb, rowptr_i, edges_i, WiT, hi1, N_ITEMS);

    // ---- layer 1 ----
    transform_fused_kernel<<<tu_blocks, 256, 0, stream>>>(hu1, hi1, rowptr_u, edges_u, WuT + 8192, out, N_USERS);
    transform_fused_kernel<<<ti_blocks, 256, 0, stream>>>(hi1, hu1, rowptr_i, edges_i, WiT + 8192, out + (size_t)N_USERS * 64, N_ITEMS);
}

// Round 5
// 1489.316 us; speedup vs baseline: 8.0717x; 1.1720x over previous
//
#include <hip/hip_runtime.h>

// GraphSAGE-CF on MI355X — round 4.
// Round-3 profile: fill_kernel 500us, WRITE_SIZE 396MB = 6.2M x 64B lines
// (scattered 8B CSR stores, zero line coalescing) + 6.4M returning atomics.
// This round: (1) rank precomputed in hist (fill has no atomics),
// (2) XCD-partitioned fill (blockIdx&7 owns rows r&7==part -> CSR lines fill
// inside one L2 before writeback; correctness independent of the mapping),
// (3) transform gather software-pipelined: 2x8 chains/wave with next-edge
// prefetch.
//
// ws layout (4-byte words), total ~143.3 MB:
//   WuT[2][128][64] @0   WiT @16384          Wt[l][k][j]=W[l][j][k]
//   hu1[200000][64] @32768                   layer-0 user out
//   hi1[100000][64] @12832768                layer-0 item out
//   edges_u uint2[3.2M] @19232768            (item_col, w_u2i bits) by user row
//   edges_i uint2[3.2M] @25632768            (user_col, w_i2u bits) by item row
//   rank_u ushort[3.2M] @32032768            per-edge rank within its row
//   rank_i ushort[3.2M] @33632768
//   rowptr_u[200001] @35232768  rowptr_i[100001]
//   deg_u[200000]  deg_i[100000]
//   bsum_u[782] bpre_u[782] bsum_i[391] bpre_i[391]

#define N_USERS 200000
#define N_ITEMS 100000
#define N_EDGES 3200000
#define NB_U 782      // ceil(200000/256)
#define NB_I 391      // ceil(100000/256)

// ---------- W convert + transpose:  Wt[l][k][j] = W[l][j][k] ----------
__global__ __launch_bounds__(256) void wprep_kernel(
    const float* __restrict__ Wu, const float* __restrict__ Wi,
    float* __restrict__ WuT, float* __restrict__ WiT)
{
    int idx = blockIdx.x * 256 + threadIdx.x;     // 0..32767
    const float* src = Wu;
    float* dst = WuT;
    int i = idx;
    if (idx >= 16384) { src = Wi; dst = WiT; i = idx - 16384; }
    int l = i >> 13;
    int r = i & 8191;
    int j = r >> 7;           // out col 0..63
    int k = r & 127;          // in  idx 0..127
    dst[l * 8192 + k * 64 + j] = src[i];
}

// ---------- degree histogram + per-edge rank (atomic return is the rank) ----
__global__ __launch_bounds__(256) void hist_kernel(
    const int* __restrict__ u_idx, const int* __restrict__ i_idx,
    int* __restrict__ deg_u, int* __restrict__ deg_i,
    unsigned short* __restrict__ rank_u, unsigned short* __restrict__ rank_i)
{
    int t = blockIdx.x * 256 + threadIdx.x;     // < 2E
    if (t < N_EDGES) {
        rank_u[t] = (unsigned short)atomicAdd(&deg_u[u_idx[t]], 1);
    } else {
        int e = t - N_EDGES;
        rank_i[e] = (unsigned short)atomicAdd(&deg_i[i_idx[e]], 1);
    }
}

// ---------- scan phase A: per-block sums ----------
__global__ __launch_bounds__(256) void scanA_kernel(
    const int* __restrict__ deg_u, const int* __restrict__ deg_i,
    int* __restrict__ bsum_u, int* __restrict__ bsum_i)
{
    int b = blockIdx.x;
    const int* deg; int n; int* bs; int bb;
    if (b < NB_U) { deg = deg_u; n = N_USERS; bs = bsum_u; bb = b; }
    else          { deg = deg_i; n = N_ITEMS; bs = bsum_i; bb = b - NB_U; }
    int i = bb * 256 + threadIdx.x;
    int v = (i < n) ? deg[i] : 0;
    #pragma unroll
    for (int off = 1; off < 64; off <<= 1) v += __shfl_xor(v, off);
    __shared__ int ws4[4];
    int wv = threadIdx.x >> 6;
    if ((threadIdx.x & 63) == 0) ws4[wv] = v;
    __syncthreads();
    if (threadIdx.x == 0) bs[bb] = ws4[0] + ws4[1] + ws4[2] + ws4[3];
}

// ---------- scan phase B: exclusive scan of block sums ----------
__global__ __launch_bounds__(1024) void scanB_kernel(
    const int* __restrict__ bsum_u, int* __restrict__ bpre_u,
    const int* __restrict__ bsum_i, int* __restrict__ bpre_i)
{
    __shared__ int s[1024];
    const int* src; int* dst; int n;
    if (blockIdx.x == 0) { src = bsum_u; dst = bpre_u; n = NB_U; }
    else                 { src = bsum_i; dst = bpre_i; n = NB_I; }
    int t = threadIdx.x;
    int v = (t < n) ? src[t] : 0;
    s[t] = v; __syncthreads();
    #pragma unroll
    for (int off = 1; off < 1024; off <<= 1) {
        int x = (t >= off) ? s[t - off] : 0;
        __syncthreads();
        s[t] += x;
        __syncthreads();
    }
    if (t < n) dst[t] = s[t] - v;   // exclusive
}

// ---------- scan phase C: rowptr = bpre + intra-block exclusive ----------
__global__ __launch_bounds__(256) void scanC_kernel(
    const int* __restrict__ deg_u, const int* __restrict__ deg_i,
    const int* __restrict__ bpre_u, const int* __restrict__ bpre_i,
    int* __restrict__ rowptr_u, int* __restrict__ rowptr_i)
{
    int b = blockIdx.x;
    const int* deg; int n; const int* bpre; int* rowptr; int bb;
    if (b < NB_U) { deg = deg_u; n = N_USERS; bpre = bpre_u; rowptr = rowptr_u; bb = b; }
    else          { deg = deg_i; n = N_ITEMS; bpre = bpre_i; rowptr = rowptr_i; bb = b - NB_U; }
    int t = threadIdx.x;
    int i = bb * 256 + t;
    int d = (i < n) ? deg[i] : 0;
    __shared__ int s[256];
    s[t] = d; __syncthreads();
    #pragma unroll
    for (int off = 1; off < 256; off <<= 1) {
        int x = (t >= off) ? s[t - off] : 0;
        __syncthreads();
        s[t] += x;
        __syncthreads();
    }
    int val = bpre[bb] + (s[t] - d);
    if (i < n) rowptr[i] = val;
    if (b == 0 && t == 0) { rowptr_u[N_USERS] = N_EDGES; rowptr_i[N_ITEMS] = N_EDGES; }
}

// ---------- CSR fill: no atomics; XCD-partitioned by destination row ----------
// Block handles only rows with (row & 7) == (blockIdx & 7). Default dispatch
// round-robins blocks over the 8 XCDs, so all writes to a CSR line come from
// one XCD's L2 -> full-line writeback. Correct for ANY block->XCD mapping.
__global__ __launch_bounds__(256) void fill_kernel(
    const int* __restrict__ u_idx, const int* __restrict__ i_idx,
    const float* __restrict__ w_u2i, const float* __restrict__ w_i2u,
    const unsigned short* __restrict__ rank_u, const unsigned short* __restrict__ rank_i,
    const int* __restrict__ rowptr_u, const int* __restrict__ rowptr_i,
    uint2* __restrict__ edges_u, uint2* __restrict__ edges_i)
{
    const int part   = blockIdx.x & 7;
    const int slot   = blockIdx.x >> 3;
    const int nslots = gridDim.x >> 3;
    const int stride = nslots * 256;

    for (int e = slot * 256 + threadIdx.x; e < N_EDGES; e += stride) {
        int ru = u_idx[e];
        int ri = i_idx[e];
        if ((ru & 7) == part) {
            int p = rowptr_u[ru] + rank_u[e];
            edges_u[p] = make_uint2((unsigned)ri, __float_as_uint(w_u2i[e]));
        }
        if ((ri & 7) == part) {
            int p = rowptr_i[ri] + rank_i[e];
            edges_i[p] = make_uint2((unsigned)ru, __float_as_uint(w_i2u[e]));
        }
    }
}

// ---------- fused gather + dense transform + relu + l2norm ----------
// Gather: wave owns 16 rows, processed as 2 passes of 8 interleaved chains
// with next-edge prefetch (edge load for it+1 issued before fma of it).
__global__ __launch_bounds__(256, 4) void transform_fused_kernel(
    const float* __restrict__ hself, const float* __restrict__ hsrc,
    const int* __restrict__ rowptr, const uint2* __restrict__ edges,
    const float* __restrict__ Wt, float* __restrict__ out, int N)
{
    __shared__ float Ws[64 * 64];    // 16 KB — one half of Wt at a time
    __shared__ float Xs[64 * 68];    // 17 KB, stride 68

    const int tid  = threadIdx.x;
    const int row0 = blockIdx.x * 64;

    // ---- stage Ws half A (k=0..63) and self-feature tile ----
    #pragma unroll
    for (int i = 0; i < 16; ++i) Ws[tid + i * 256] = Wt[tid + i * 256];
    #pragma unroll
    for (int i = 0; i < 16; ++i) {
        int idx = tid + i * 256;
        int rr = idx >> 6, cc = idx & 63;
        int gr = row0 + rr; if (gr > N - 1) gr = N - 1;
        Xs[rr * 68 + cc] = hself[gr * 64 + cc];
    }
    __syncthreads();

    const int tr = tid >> 3;     // 0..31
    const int tc = tid & 7;      // 0..7
    const int r0 = 2 * tr;

    float acc[2][8];
    #pragma unroll
    for (int j = 0; j < 2; ++j)
        #pragma unroll
        for (int c = 0; c < 8; ++c) acc[j][c] = 0.f;

    // ---- GEMM phase A: self features ----
    #pragma unroll 8
    for (int k = 0; k < 64; ++k) {
        float a0 = Xs[r0 * 68 + k];
        float a1 = Xs[(r0 + 1) * 68 + k];
        float4 b0 = *(const float4*)&Ws[k * 64 + 8 * tc];
        float4 b1 = *(const float4*)&Ws[k * 64 + 8 * tc + 4];
        float b[8] = {b0.x, b0.y, b0.z, b0.w, b1.x, b1.y, b1.z, b1.w};
        #pragma unroll
        for (int c = 0; c < 8; ++c) {
            acc[0][c] = fmaf(a0, b[c], acc[0][c]);
            acc[1][c] = fmaf(a1, b[c], acc[1][c]);
        }
    }
    __syncthreads();   // all waves done with Ws-A and self Xs

    // ---- reload Ws half B (k=64..127) ----
    {
        const float4* src = (const float4*)(Wt + 4096);
        float4* dst = (float4*)Ws;
        #pragma unroll
        for (int i = 0; i < 4; ++i) dst[tid + i * 256] = src[tid + i * 256];
    }

    // ---- gather: wave wv owns rows [wv*16, wv*16+16), lane = feature ----
    {
        const int wv = tid >> 6;
        const int ln = tid & 63;
        #pragma unroll 1
        for (int half = 0; half < 2; ++half) {
            const int rbase = row0 + wv * 16 + half * 8;
            int   ecur[8], eend[8];
            float gacc[8];
            #pragma unroll
            for (int rl = 0; rl < 8; ++rl) {
                int r = rbase + rl;
                if (r < N) { ecur[rl] = rowptr[r]; eend[rl] = rowptr[r + 1]; }
                else       { ecur[rl] = 0;         eend[rl] = 0; }
                gacc[rl] = 0.f;
            }
            int dmax = 0;
            #pragma unroll
            for (int rl = 0; rl < 8; ++rl) dmax = max(dmax, eend[rl] - ecur[rl]);

            uint2 ec[8];
            #pragma unroll
            for (int rl = 0; rl < 8; ++rl)
                ec[rl] = edges[min(ecur[rl], N_EDGES - 1)];

            #pragma unroll 1
            for (int it = 0; it < dmax; ++it) {
                float hv[8], wg[8];
                // consume current edges: issue 8 independent gathers
                #pragma unroll
                for (int rl = 0; rl < 8; ++rl) {
                    bool v = ecur[rl] < eend[rl];
                    wg[rl] = v ? __uint_as_float(ec[rl].y) : 0.f;
                    hv[rl] = hsrc[(int)ec[rl].x * 64 + ln];
                    ecur[rl] += v ? 1 : 0;
                }
                // prefetch next edges while gathers are in flight
                #pragma unroll
                for (int rl = 0; rl < 8; ++rl)
                    ec[rl] = edges[min(ecur[rl], N_EDGES - 1)];
                #pragma unroll
                for (int rl = 0; rl < 8; ++rl)
                    gacc[rl] = fmaf(wg[rl], hv[rl], gacc[rl]);
            }
            #pragma unroll
            for (int rl = 0; rl < 8; ++rl)
                Xs[(wv * 16 + half * 8 + rl) * 68 + ln] = gacc[rl];
        }
    }
    __syncthreads();

    // ---- GEMM phase B: neighbor features ----
    #pragma unroll 8
    for (int k = 0; k < 64; ++k) {
        float a0 = Xs[r0 * 68 + k];
        float a1 = Xs[(r0 + 1) * 68 + k];
        float4 b0 = *(const float4*)&Ws[k * 64 + 8 * tc];
        float4 b1 = *(const float4*)&Ws[k * 64 + 8 * tc + 4];
        float b[8] = {b0.x, b0.y, b0.z, b0.w, b1.x, b1.y, b1.z, b1.w};
        #pragma unroll
        for (int c = 0; c < 8; ++c) {
            acc[0][c] = fmaf(a0, b[c], acc[0][c]);
            acc[1][c] = fmaf(a1, b[c], acc[1][c]);
        }
    }

    // ---- epilogue: relu, row L2 norm (8 lanes per row), store ----
    #pragma unroll
    for (int j = 0; j < 2; ++j) {
        float s = 0.f;
        #pragma unroll
        for (int c = 0; c < 8; ++c) {
            float v = fmaxf(acc[j][c], 0.f);
            acc[j][c] = v;
            s = fmaf(v, v, s);
        }
        s += __shfl_xor(s, 1);
        s += __shfl_xor(s, 2);
        s += __shfl_xor(s, 4);
        float nrm = sqrtf(s);
        float inv = 1.f / fmaxf(nrm, 1e-12f);
        int gr = row0 + r0 + j;
        if (gr < N) {
            float4 o0 = make_float4(acc[j][0]*inv, acc[j][1]*inv, acc[j][2]*inv, acc[j][3]*inv);
            float4 o1 = make_float4(acc[j][4]*inv, acc[j][5]*inv, acc[j][6]*inv, acc[j][7]*inv);
            float* p = out + gr * 64 + 8 * tc;
            *(float4*)p       = o0;
            *(float4*)(p + 4) = o1;
        }
    }
}

extern "C" void kernel_launch(void* const* d_in, const int* in_sizes, int n_in,
                              void* d_out, int out_size, void* d_ws, size_t ws_size,
                              hipStream_t stream)
{
    (void)in_sizes; (void)n_in; (void)out_size; (void)ws_size;

    const float* user_emb = (const float*)d_in[0];
    const float* item_emb = (const float*)d_in[1];
    const float* Wu       = (const float*)d_in[2];
    const float* Wi       = (const float*)d_in[3];
    const int*   u_idx    = (const int*)d_in[4];
    const int*   i_idx    = (const int*)d_in[5];
    const float* w_u2i    = (const float*)d_in[6];
    const float* w_i2u    = (const float*)d_in[7];
    float* out = (float*)d_out;

    float* ws      = (float*)d_ws;
    float* WuT     = ws;                            // 16384
    float* WiT     = WuT + 16384;                   // 16384
    float* hu1     = WiT + 16384;                   // 12,800,000
    float* hi1     = hu1 + N_USERS * 64;            // 6,400,000
    uint2* edges_u = (uint2*)(hi1 + N_ITEMS * 64);  // 3.2M uint2
    uint2* edges_i = edges_u + N_EDGES;             // 3.2M uint2
    unsigned short* rank_u = (unsigned short*)(edges_i + N_EDGES);  // 3.2M ushort
    unsigned short* rank_i = rank_u + N_EDGES;                      // 3.2M ushort
    int* rowptr_u = (int*)(rank_i + N_EDGES);       // 200001
    int* rowptr_i = rowptr_u + (N_USERS + 1);       // 100001
    int* deg_u    = rowptr_i + (N_ITEMS + 1);       // 200000
    int* deg_i    = deg_u + N_USERS;                // 100000
    int* bsum_u   = deg_i + N_ITEMS;
    int* bpre_u   = bsum_u + NB_U;
    int* bsum_i   = bpre_u + NB_U;
    int* bpre_i   = bsum_i + NB_I;

    const int tu_blocks = (N_USERS + 63) / 64;        // 3125
    const int ti_blocks = (N_ITEMS + 63) / 64;        // 1563
    const int e2_blocks = (2 * N_EDGES) / 256;        // 25000

    // ---- CSR build (both sides) ----
    wprep_kernel<<<128, 256, 0, stream>>>(Wu, Wi, WuT, WiT);
    hipMemsetAsync(deg_u, 0, (size_t)(N_USERS + N_ITEMS) * 4, stream);
    hist_kernel<<<e2_blocks, 256, 0, stream>>>(u_idx, i_idx, deg_u, deg_i, rank_u, rank_i);
    scanA_kernel<<<NB_U + NB_I, 256, 0, stream>>>(deg_u, deg_i, bsum_u, bsum_i);
    scanB_kernel<<<2, 1024, 0, stream>>>(bsum_u, bpre_u, bsum_i, bpre_i);
    scanC_kernel<<<NB_U + NB_I, 256, 0, stream>>>(deg_u, deg_i, bpre_u, bpre_i, rowptr_u, rowptr_i);
    fill_kernel<<<2048, 256, 0, stream>>>(u_idx, i_idx, w_u2i, w_i2u,
                                          rank_u, rank_i, rowptr_u, rowptr_i,
                                          edges_u, edges_i);

    // ---- layer 0 ----
    transform_fused_kernel<<<tu_blocks, 256, 0, stream>>>(user_emb, item_emb, rowptr_u, edges_u, WuT, hu1, N_USERS);
    transform_fused_kernel<<<ti_blocks, 256, 0, stream>>>(item_emb, user_emb, rowptr_i, edges_i, WiT, hi1, N_ITEMS);

    // ---- layer 1 ----
    transform_fused_kernel<<<tu_blocks, 256, 0, stream>>>(hu1, hi1, rowptr_u, edges_u, WuT + 8192, out, N_USERS);
    transform_fused_kernel<<<ti_blocks, 256, 0, stream>>>(hi1, hu1, rowptr_i, edges_i, WiT + 8192, out + (size_t)N_USERS * 64, N_ITEMS);
}

// Round 6
// 1347.722 us; speedup vs baseline: 8.9197x; 1.1051x over previous
//
#include <hip/hip_runtime.h>

// GraphSAGE-CF on MI355X — round 5.
// Round-4 profile: hist 260us = 6.4M device atomics at the measured ~25G/s
// memory-side atomic ceiling (structural floor; WRITE 212MB = 32B/atomic).
// Transforms all <260us but ~1.6x lockstep waste in the 8-chain gather
// (iterations = max(deg of 8 rows) vs mean, dead slots issue real gathers).
// This round: (1) edge-balanced gather — each wave walks a contiguous 1/4 of
// the block's edge range as 8 equal sub-chains, flushing per-row partials
// into Xs via LDS atomicAdd (ds_add_f32); zero waste, zero dead gathers.
// (2) u-side + i-side transforms merged into one dispatch per layer.
//
// ws layout (4-byte words):
//   WuT[2][128][64] @0   WiT @16384          Wt[l][k][j]=W[l][j][k]
//   hu1[200000][64]                          layer-0 user out
//   hi1[100000][64]                          layer-0 item out
//   edges_u uint2[3.2M]                      (item_col, w bits) by user row
//   edges_i uint2[3.2M]                      (user_col, w bits) by item row
//   rank_u ushort[3.2M]  rank_i ushort[3.2M]
//   rowptr_u[200001]  rowptr_i[100001]
//   deg_u[200000]  deg_i[100000]
//   bsum_u[782] bpre_u[782] bsum_i[391] bpre_i[391]

#define N_USERS 200000
#define N_ITEMS 100000
#define N_EDGES 3200000
#define NB_U 782      // ceil(200000/256)
#define NB_I 391      // ceil(100000/256)

// ---------- W convert + transpose:  Wt[l][k][j] = W[l][j][k] ----------
__global__ __launch_bounds__(256) void wprep_kernel(
    const float* __restrict__ Wu, const float* __restrict__ Wi,
    float* __restrict__ WuT, float* __restrict__ WiT)
{
    int idx = blockIdx.x * 256 + threadIdx.x;     // 0..32767
    const float* src = Wu;
    float* dst = WuT;
    int i = idx;
    if (idx >= 16384) { src = Wi; dst = WiT; i = idx - 16384; }
    int l = i >> 13;
    int r = i & 8191;
    int j = r >> 7;           // out col 0..63
    int k = r & 127;          // in  idx 0..127
    dst[l * 8192 + k * 64 + j] = src[i];
}

// ---------- degree histogram + per-edge rank (atomic return is the rank) ----
__global__ __launch_bounds__(256) void hist_kernel(
    const int* __restrict__ u_idx, const int* __restrict__ i_idx,
    int* __restrict__ deg_u, int* __restrict__ deg_i,
    unsigned short* __restrict__ rank_u, unsigned short* __restrict__ rank_i)
{
    int t = blockIdx.x * 256 + threadIdx.x;     // < 2E
    if (t < N_EDGES) {
        rank_u[t] = (unsigned short)atomicAdd(&deg_u[u_idx[t]], 1);
    } else {
        int e = t - N_EDGES;
        rank_i[e] = (unsigned short)atomicAdd(&deg_i[i_idx[e]], 1);
    }
}

// ---------- scan phase A: per-block sums ----------
__global__ __launch_bounds__(256) void scanA_kernel(
    const int* __restrict__ deg_u, const int* __restrict__ deg_i,
    int* __restrict__ bsum_u, int* __restrict__ bsum_i)
{
    int b = blockIdx.x;
    const int* deg; int n; int* bs; int bb;
    if (b < NB_U) { deg = deg_u; n = N_USERS; bs = bsum_u; bb = b; }
    else          { deg = deg_i; n = N_ITEMS; bs = bsum_i; bb = b - NB_U; }
    int i = bb * 256 + threadIdx.x;
    int v = (i < n) ? deg[i] : 0;
    #pragma unroll
    for (int off = 1; off < 64; off <<= 1) v += __shfl_xor(v, off);
    __shared__ int ws4[4];
    int wv = threadIdx.x >> 6;
    if ((threadIdx.x & 63) == 0) ws4[wv] = v;
    __syncthreads();
    if (threadIdx.x == 0) bs[bb] = ws4[0] + ws4[1] + ws4[2] + ws4[3];
}

// ---------- scan phase B: exclusive scan of block sums ----------
__global__ __launch_bounds__(1024) void scanB_kernel(
    const int* __restrict__ bsum_u, int* __restrict__ bpre_u,
    const int* __restrict__ bsum_i, int* __restrict__ bpre_i)
{
    __shared__ int s[1024];
    const int* src; int* dst; int n;
    if (blockIdx.x == 0) { src = bsum_u; dst = bpre_u; n = NB_U; }
    else                 { src = bsum_i; dst = bpre_i; n = NB_I; }
    int t = threadIdx.x;
    int v = (t < n) ? src[t] : 0;
    s[t] = v; __syncthreads();
    #pragma unroll
    for (int off = 1; off < 1024; off <<= 1) {
        int x = (t >= off) ? s[t - off] : 0;
        __syncthreads();
        s[t] += x;
        __syncthreads();
    }
    if (t < n) dst[t] = s[t] - v;   // exclusive
}

// ---------- scan phase C: rowptr = bpre + intra-block exclusive ----------
__global__ __launch_bounds__(256) void scanC_kernel(
    const int* __restrict__ deg_u, const int* __restrict__ deg_i,
    const int* __restrict__ bpre_u, const int* __restrict__ bpre_i,
    int* __restrict__ rowptr_u, int* __restrict__ rowptr_i)
{
    int b = blockIdx.x;
    const int* deg; int n; const int* bpre; int* rowptr; int bb;
    if (b < NB_U) { deg = deg_u; n = N_USERS; bpre = bpre_u; rowptr = rowptr_u; bb = b; }
    else          { deg = deg_i; n = N_ITEMS; bpre = bpre_i; rowptr = rowptr_i; bb = b - NB_U; }
    int t = threadIdx.x;
    int i = bb * 256 + t;
    int d = (i < n) ? deg[i] : 0;
    __shared__ int s[256];
    s[t] = d; __syncthreads();
    #pragma unroll
    for (int off = 1; off < 256; off <<= 1) {
        int x = (t >= off) ? s[t - off] : 0;
        __syncthreads();
        s[t] += x;
        __syncthreads();
    }
    int val = bpre[bb] + (s[t] - d);
    if (i < n) rowptr[i] = val;
    if (b == 0 && t == 0) { rowptr_u[N_USERS] = N_EDGES; rowptr_i[N_ITEMS] = N_EDGES; }
}

// ---------- CSR fill: no atomics; XCD-partitioned by destination row ----------
__global__ __launch_bounds__(256) void fill_kernel(
    const int* __restrict__ u_idx, const int* __restrict__ i_idx,
    const float* __restrict__ w_u2i, const float* __restrict__ w_i2u,
    const unsigned short* __restrict__ rank_u, const unsigned short* __restrict__ rank_i,
    const int* __restrict__ rowptr_u, const int* __restrict__ rowptr_i,
    uint2* __restrict__ edges_u, uint2* __restrict__ edges_i)
{
    const int part   = blockIdx.x & 7;
    const int slot   = blockIdx.x >> 3;
    const int nslots = gridDim.x >> 3;
    const int stride = nslots * 256;

    for (int e = slot * 256 + threadIdx.x; e < N_EDGES; e += stride) {
        int ru = u_idx[e];
        int ri = i_idx[e];
        if ((ru & 7) == part) {
            int p = rowptr_u[ru] + rank_u[e];
            edges_u[p] = make_uint2((unsigned)ri, __float_as_uint(w_u2i[e]));
        }
        if ((ri & 7) == part) {
            int p = rowptr_i[ri] + rank_i[e];
            edges_i[p] = make_uint2((unsigned)ru, __float_as_uint(w_i2u[e]));
        }
    }
}

// ---------- fused gather + dense transform + relu + l2norm (both sides) ----------
// Gather: block edge range [rowptr[row0], rowptr[row0+64]) split into 4 wave
// chunks, each into 8 equal contiguous sub-chains (balance within +-1 edge).
// Per-row partial sums flushed to Xs via LDS atomicAdd (ds_add_f32).
__global__ __launch_bounds__(256, 4) void transform_fused_kernel(
    const float* __restrict__ hself_u, const float* __restrict__ hsrc_u,
    const int* __restrict__ rowptr_u, const uint2* __restrict__ edges_u,
    const float* __restrict__ WtU, float* __restrict__ out_u,
    const float* __restrict__ hself_i, const float* __restrict__ hsrc_i,
    const int* __restrict__ rowptr_i, const uint2* __restrict__ edges_i,
    const float* __restrict__ WtI, float* __restrict__ out_i,
    int nbu)
{
    __shared__ float Ws[64 * 64];    // 16 KB — one half of Wt at a time
    __shared__ float Xs[64 * 68];    // 17 KB, stride 68
    __shared__ int   rp_s[65];

    const int tid = threadIdx.x;

    const float* hself; const float* hsrc; const int* rowptr;
    const uint2* edges; const float* Wt; float* out; int N; int bb;
    if ((int)blockIdx.x < nbu) {
        hself = hself_u; hsrc = hsrc_u; rowptr = rowptr_u; edges = edges_u;
        Wt = WtU; out = out_u; N = N_USERS; bb = blockIdx.x;
    } else {
        hself = hself_i; hsrc = hsrc_i; rowptr = rowptr_i; edges = edges_i;
        Wt = WtI; out = out_i; N = N_ITEMS; bb = blockIdx.x - nbu;
    }
    const int row0 = bb * 64;

    // ---- stage Ws half A (k=0..63) + self tile + rowptr slice ----
    #pragma unroll
    for (int i = 0; i < 16; ++i) Ws[tid + i * 256] = Wt[tid + i * 256];
    #pragma unroll
    for (int i = 0; i < 16; ++i) {
        int idx = tid + i * 256;
        int rr = idx >> 6, cc = idx & 63;
        int gr = row0 + rr; if (gr > N - 1) gr = N - 1;
        Xs[rr * 68 + cc] = hself[gr * 64 + cc];
    }
    if (tid <= 64) rp_s[tid] = rowptr[min(row0 + tid, N)];
    __syncthreads();

    const int tr = tid >> 3;     // 0..31
    const int tc = tid & 7;      // 0..7
    const int r0 = 2 * tr;

    float acc[2][8];
    #pragma unroll
    for (int j = 0; j < 2; ++j)
        #pragma unroll
        for (int c = 0; c < 8; ++c) acc[j][c] = 0.f;

    // ---- GEMM phase A: self features ----
    #pragma unroll 8
    for (int k = 0; k < 64; ++k) {
        float a0 = Xs[r0 * 68 + k];
        float a1 = Xs[(r0 + 1) * 68 + k];
        float4 b0 = *(const float4*)&Ws[k * 64 + 8 * tc];
        float4 b1 = *(const float4*)&Ws[k * 64 + 8 * tc + 4];
        float b[8] = {b0.x, b0.y, b0.z, b0.w, b1.x, b1.y, b1.z, b1.w};
        #pragma unroll
        for (int c = 0; c < 8; ++c) {
            acc[0][c] = fmaf(a0, b[c], acc[0][c]);
            acc[1][c] = fmaf(a1, b[c], acc[1][c]);
        }
    }
    __syncthreads();   // done with Ws-A and self Xs

    // ---- reload Ws half B; zero Xs ----
    {
        const float4* src = (const float4*)(Wt + 4096);
        float4* dst = (float4*)Ws;
        #pragma unroll
        for (int i = 0; i < 4; ++i) dst[tid + i * 256] = src[tid + i * 256];
        #pragma unroll
        for (int i = 0; i < 17; ++i) Xs[tid + i * 256] = 0.f;   // 17*256 == 64*68
    }
    __syncthreads();

    // ---- edge-balanced gather, LDS-atomic flush ----
    {
        const int wv = tid >> 6;
        const int ln = tid & 63;
        const int e0 = rp_s[0], e1 = rp_s[64];
        const int perw = (e1 - e0 + 3) >> 2;
        const int wsb  = e0 + wv * perw;
        const int web  = min(wsb + perw, e1);
        const int clen = (web - wsb + 7) >> 3;

        int   cs[8], ce[8], rr[8], nend[8];
        float gacc[8];
        uint2 ec[8];
        #pragma unroll
        for (int c = 0; c < 8; ++c) {
            cs[c] = wsb + c * clen;
            ce[c] = min(cs[c] + clen, web);
            gacc[c] = 0.f;
            int lo = 0, hi = 64;                     // find row owning cs[c]
            #pragma unroll
            for (int s = 0; s < 6; ++s) {
                int mid = (lo + hi) >> 1;
                bool go = rp_s[mid] <= cs[c];
                lo = go ? mid : lo;
                hi = go ? hi : mid;
            }
            rr[c] = lo; nend[c] = rp_s[lo + 1];
            ec[c] = edges[min(cs[c], N_EDGES - 1)];
        }

        #pragma unroll 1
        for (int it = 0; it < clen; ++it) {
            float hv[8], wg[8];
            #pragma unroll
            for (int c = 0; c < 8; ++c) {
                bool v = (cs[c] + it) < ce[c];
                wg[c] = v ? __uint_as_float(ec[c].y) : 0.f;
                hv[c] = hsrc[(int)ec[c].x * 64 + ln];
            }
            #pragma unroll
            for (int c = 0; c < 8; ++c)
                ec[c] = edges[min(cs[c] + it + 1, N_EDGES - 1)];
            #pragma unroll
            for (int c = 0; c < 8; ++c) {
                gacc[c] = fmaf(wg[c], hv[c], gacc[c]);
                int p   = cs[c] + it;
                int nxt = p + 1;
                if (p < ce[c] && (nxt == nend[c] || nxt == ce[c])) {
                    atomicAdd(&Xs[rr[c] * 68 + ln], gacc[c]);   // ds_add_f32
                    gacc[c] = 0.f;
                    if (nxt == nend[c] && nxt < web) {
                        int r2 = rr[c];
                        while (r2 < 63 && rp_s[r2 + 1] <= nxt) ++r2;
                        rr[c] = r2; nend[c] = rp_s[r2 + 1];
                    }
                }
            }
        }
    }
    __syncthreads();

    // ---- GEMM phase B: neighbor features ----
    #pragma unroll 8
    for (int k = 0; k < 64; ++k) {
        float a0 = Xs[r0 * 68 + k];
        float a1 = Xs[(r0 + 1) * 68 + k];
        float4 b0 = *(const float4*)&Ws[k * 64 + 8 * tc];
        float4 b1 = *(const float4*)&Ws[k * 64 + 8 * tc + 4];
        float b[8] = {b0.x, b0.y, b0.z, b0.w, b1.x, b1.y, b1.z, b1.w};
        #pragma unroll
        for (int c = 0; c < 8; ++c) {
            acc[0][c] = fmaf(a0, b[c], acc[0][c]);
            acc[1][c] = fmaf(a1, b[c], acc[1][c]);
        }
    }

    // ---- epilogue: relu, row L2 norm (8 lanes per row), store ----
    #pragma unroll
    for (int j = 0; j < 2; ++j) {
        float s = 0.f;
        #pragma unroll
        for (int c = 0; c < 8; ++c) {
            float v = fmaxf(acc[j][c], 0.f);
            acc[j][c] = v;
            s = fmaf(v, v, s);
        }
        s += __shfl_xor(s, 1);
        s += __shfl_xor(s, 2);
        s += __shfl_xor(s, 4);
        float nrm = sqrtf(s);
        float inv = 1.f / fmaxf(nrm, 1e-12f);
        int gr = row0 + r0 + j;
        if (gr < N) {
            float4 o0 = make_float4(acc[j][0]*inv, acc[j][1]*inv, acc[j][2]*inv, acc[j][3]*inv);
            float4 o1 = make_float4(acc[j][4]*inv, acc[j][5]*inv, acc[j][6]*inv, acc[j][7]*inv);
            float* p = out + gr * 64 + 8 * tc;
            *(float4*)p       = o0;
            *(float4*)(p + 4) = o1;
        }
    }
}

extern "C" void kernel_launch(void* const* d_in, const int* in_sizes, int n_in,
                              void* d_out, int out_size, void* d_ws, size_t ws_size,
                              hipStream_t stream)
{
    (void)in_sizes; (void)n_in; (void)out_size; (void)ws_size;

    const float* user_emb = (const float*)d_in[0];
    const float* item_emb = (const float*)d_in[1];
    const float* Wu       = (const float*)d_in[2];
    const float* Wi       = (const float*)d_in[3];
    const int*   u_idx    = (const int*)d_in[4];
    const int*   i_idx    = (const int*)d_in[5];
    const float* w_u2i    = (const float*)d_in[6];
    const float* w_i2u    = (const float*)d_in[7];
    float* out = (float*)d_out;

    float* ws      = (float*)d_ws;
    float* WuT     = ws;                            // 16384
    float* WiT     = WuT + 16384;                   // 16384
    float* hu1     = WiT + 16384;                   // 12,800,000
    float* hi1     = hu1 + N_USERS * 64;            // 6,400,000
    uint2* edges_u = (uint2*)(hi1 + N_ITEMS * 64);  // 3.2M uint2
    uint2* edges_i = edges_u + N_EDGES;             // 3.2M uint2
    unsigned short* rank_u = (unsigned short*)(edges_i + N_EDGES);  // 3.2M ushort
    unsigned short* rank_i = rank_u + N_EDGES;                      // 3.2M ushort
    int* rowptr_u = (int*)(rank_i + N_EDGES);       // 200001
    int* rowptr_i = rowptr_u + (N_USERS + 1);       // 100001
    int* deg_u    = rowptr_i + (N_ITEMS + 1);       // 200000
    int* deg_i    = deg_u + N_USERS;                // 100000
    int* bsum_u   = deg_i + N_ITEMS;
    int* bpre_u   = bsum_u + NB_U;
    int* bsum_i   = bpre_u + NB_U;
    int* bpre_i   = bsum_i + NB_I;

    const int tu_blocks = (N_USERS + 63) / 64;        // 3125
    const int ti_blocks = (N_ITEMS + 63) / 64;        // 1563
    const int e2_blocks = (2 * N_EDGES) / 256;        // 25000

    // ---- CSR build (both sides) ----
    wprep_kernel<<<128, 256, 0, stream>>>(Wu, Wi, WuT, WiT);
    hipMemsetAsync(deg_u, 0, (size_t)(N_USERS + N_ITEMS) * 4, stream);
    hist_kernel<<<e2_blocks, 256, 0, stream>>>(u_idx, i_idx, deg_u, deg_i, rank_u, rank_i);
    scanA_kernel<<<NB_U + NB_I, 256, 0, stream>>>(deg_u, deg_i, bsum_u, bsum_i);
    scanB_kernel<<<2, 1024, 0, stream>>>(bsum_u, bpre_u, bsum_i, bpre_i);
    scanC_kernel<<<NB_U + NB_I, 256, 0, stream>>>(deg_u, deg_i, bpre_u, bpre_i, rowptr_u, rowptr_i);
    fill_kernel<<<2048, 256, 0, stream>>>(u_idx, i_idx, w_u2i, w_i2u,
                                          rank_u, rank_i, rowptr_u, rowptr_i,
                                          edges_u, edges_i);

    // ---- layer 0 (u + i in one dispatch) ----
    transform_fused_kernel<<<tu_blocks + ti_blocks, 256, 0, stream>>>(
        user_emb, item_emb, rowptr_u, edges_u, WuT, hu1,
        item_emb, user_emb, rowptr_i, edges_i, WiT, hi1, tu_blocks);

    // ---- layer 1 (u + i in one dispatch) ----
    transform_fused_kernel<<<tu_blocks + ti_blocks, 256, 0, stream>>>(
        hu1, hi1, rowptr_u, edges_u, WuT + 8192, out,
        hi1, hu1, rowptr_i, edges_i, WiT + 8192, out + (size_t)N_USERS * 64, tu_blocks);
}